// Round 5
// baseline (772.500 us; speedup 1.0000x reference)
//
#include <hip/hip_runtime.h>

#define N_ 4
#define H_ 128
#define W_ 128
#define C_ 256
#define P2_ 64
#define CELLS_ 16
#define HEADS_ 8
#define TOPK_ 4
#define SCALE_ 0.0625f
#define TOK_ (N_*H_*W_)   // 65536

typedef short short8 __attribute__((ext_vector_type(8)));
typedef float f32x4  __attribute__((ext_vector_type(4)));

// fp32 -> bf16 hi (truncate, exact) + lo (RNE of residual)
__device__ __forceinline__ void split1(float f, ushort& h, ushort& l) {
    unsigned u = __float_as_uint(f);
    h = (ushort)(u >> 16);
    float hif = __uint_as_float(u & 0xFFFF0000u);
    unsigned ul = __float_as_uint(f - hif);
    ul = ul + 0x7FFFu + ((ul >> 16) & 1u);
    l = (ushort)(ul >> 16);
}

// ---------------- pooling: xpool (4x4 cells) + window means ----------------
__global__ __launch_bounds__(256) void pool_kernel(
    const float* __restrict__ x1, const float* __restrict__ x2,
    float* __restrict__ xpool, float* __restrict__ xwm)
{
    int c = threadIdx.x;
    int blk = blockIdx.x;            // [0, 2*N*P2)
    int b   = blk >> 8;
    int rem = blk & 255;
    int n   = rem >> 6;
    int win = rem & 63;
    int wh = win >> 3, ww = win & 7;
    const float* x = (b ? x2 : x1);
    size_t nbase = (size_t)n * H_ * W_ * C_;
    size_t prow = (size_t)(b*N_ + n)*P2_ + win;
    float wsum = 0.f;
    #pragma unroll
    for (int cell = 0; cell < 16; ++cell) {
        int a = cell >> 2, d = cell & 3;
        int h0 = wh*16 + a*4, w0 = ww*16 + d*4;
        float s = 0.f;
        #pragma unroll
        for (int dy = 0; dy < 4; ++dy)
            #pragma unroll
            for (int dx = 0; dx < 4; ++dx)
                s += x[nbase + ((size_t)(h0+dy)*W_ + (w0+dx))*C_ + c];
        xpool[(prow*CELLS_ + cell)*C_ + c] = s * (1.f/16.f);
        wsum += s;
    }
    xwm[prow*C_ + c] = wsum * (1.f/256.f);
}

// ---------------- W pre-split: fp32 -> bf16 hi (truncate) + lo (RNE) --------
__global__ __launch_bounds__(256) void wsplit_kernel(
    const float* __restrict__ Wqkv, const float* __restrict__ Wo,
    ushort* __restrict__ Wh, ushort* __restrict__ Wl)
{
    int e = (blockIdx.x*256 + threadIdx.x) * 4;
    const float* src = (e < 768*256) ? (Wqkv + e) : (Wo + (e - 768*256));
    float4 f = *(const float4*)src;
    float fv[4] = {f.x, f.y, f.z, f.w};
    ushort hu[4], lu[4];
    #pragma unroll
    for (int j = 0; j < 4; ++j) split1(fv[j], hu[j], lu[j]);
    *(uint2*)&Wh[e] = *(uint2*)hu;
    *(uint2*)&Wl[e] = *(uint2*)lu;
}

#define AST 40   // LDS row stride (ushorts) = 80 B -> <=2-way bank alias

// ---------------- dual-panel MFMA GEMM: one A-stage, two 256-col W panels ---
// Block: 64 rows x 512 cols (panel Q = W rows [wbQ,wbQ+256), panel V =
// [wbV,wbV+256)). 4 waves, wave-tile 64x64 per panel (acc 4x(4+4)).
// A fp32 split on the fly through LDS (half the per-output A cost of a
// 256-col tile); B read directly global->register (L2-hot). Two-pass panel
// processing keeps B-frag live range = one panel. blockIdx.y picks slice
// {A, outputs} for batching independent inputs.
__global__ __launch_bounds__(256,2) void gemm_dual(
    const float* __restrict__ A0, const float* __restrict__ A1,
    const ushort* __restrict__ Wh, const ushort* __restrict__ Wl,
    int wbQ, int wbV,
    const float* __restrict__ bQ, const float* __restrict__ bV,
    float* __restrict__ oQ0, float* __restrict__ oV0,
    float* __restrict__ oQ1, float* __restrict__ oV1,
    int osQ, int osV)
{
    __shared__ ushort Ah[64*AST], Al[64*AST];     // 5120 B each
    int y = blockIdx.y;
    const float* A = y ? A1 : A0;
    float* oQ      = y ? oQ1 : oQ0;
    float* oV      = y ? oV1 : oV0;

    int tid = threadIdx.x;
    int row0 = blockIdx.x * 64;
    int wv = tid >> 6, lane = tid & 63;
    int quad = lane >> 4, l15 = lane & 15;

    f32x4 acc[4][8];
    #pragma unroll
    for (int mt = 0; mt < 4; ++mt)
        #pragma unroll
        for (int nt = 0; nt < 8; ++nt)
            acc[mt][nt] = f32x4{0.f, 0.f, 0.f, 0.f};

    int srow = tid >> 2;            // 0..63
    int skk  = (tid & 3) * 8;       // 0,8,16,24
    const float*  aptr = A  + (size_t)(row0 + srow)*256 + skk;
    const ushort* whQ = Wh + (size_t)(wbQ + wv*64 + l15)*256 + quad*8;
    const ushort* wlQ = Wl + (size_t)(wbQ + wv*64 + l15)*256 + quad*8;
    const ushort* whV = Wh + (size_t)(wbV + wv*64 + l15)*256 + quad*8;
    const ushort* wlV = Wl + (size_t)(wbV + wv*64 + l15)*256 + quad*8;

    for (int ck = 0; ck < 256; ck += 32) {
        // ---- Q-panel B frags (global, L2-hot), issued before the barrier ----
        short8 bh[4], bl[4];
        #pragma unroll
        for (int nt = 0; nt < 4; ++nt) {
            bh[nt] = *(const short8*)(whQ + (size_t)nt*16*256 + ck);
            bl[nt] = *(const short8*)(wlQ + (size_t)nt*16*256 + ck);
        }
        // ---- stage A chunk (64x32 fp32 -> split bf16), 8 elems/thread ----
        float4 f0 = *(const float4*)(aptr + ck);
        float4 f1 = *(const float4*)(aptr + ck + 4);
        float fv[8] = {f0.x,f0.y,f0.z,f0.w, f1.x,f1.y,f1.z,f1.w};
        ushort hu[8], lu[8];
        #pragma unroll
        for (int j = 0; j < 8; ++j) split1(fv[j], hu[j], lu[j]);
        *(uint4*)&Ah[srow*AST + skk] = *(uint4*)hu;
        *(uint4*)&Al[srow*AST + skk] = *(uint4*)lu;
        __syncthreads();
        // ---- V-panel B frags issued now; latency hides under Q MFMAs ----
        short8 ch[4], cl[4];
        #pragma unroll
        for (int nt = 0; nt < 4; ++nt) {
            ch[nt] = *(const short8*)(whV + (size_t)nt*16*256 + ck);
            cl[nt] = *(const short8*)(wlV + (size_t)nt*16*256 + ck);
        }
        // ---- pass 1: Q panel ----
        #pragma unroll
        for (int mt = 0; mt < 4; ++mt) {
            int r = mt*16 + l15;
            short8 ah = *(const short8*)&Ah[r*AST + quad*8];
            short8 al = *(const short8*)&Al[r*AST + quad*8];
            #pragma unroll
            for (int nt = 0; nt < 4; ++nt) {
                acc[mt][nt] = __builtin_amdgcn_mfma_f32_16x16x32_bf16(ah, bh[nt], acc[mt][nt], 0, 0, 0);
                acc[mt][nt] = __builtin_amdgcn_mfma_f32_16x16x32_bf16(ah, bl[nt], acc[mt][nt], 0, 0, 0);
                acc[mt][nt] = __builtin_amdgcn_mfma_f32_16x16x32_bf16(al, bh[nt], acc[mt][nt], 0, 0, 0);
            }
        }
        // ---- pass 2: V panel ----
        #pragma unroll
        for (int mt = 0; mt < 4; ++mt) {
            int r = mt*16 + l15;
            short8 ah = *(const short8*)&Ah[r*AST + quad*8];
            short8 al = *(const short8*)&Al[r*AST + quad*8];
            #pragma unroll
            for (int nt = 0; nt < 4; ++nt) {
                acc[mt][nt+4] = __builtin_amdgcn_mfma_f32_16x16x32_bf16(ah, ch[nt], acc[mt][nt+4], 0, 0, 0);
                acc[mt][nt+4] = __builtin_amdgcn_mfma_f32_16x16x32_bf16(ah, cl[nt], acc[mt][nt+4], 0, 0, 0);
                acc[mt][nt+4] = __builtin_amdgcn_mfma_f32_16x16x32_bf16(al, ch[nt], acc[mt][nt+4], 0, 0, 0);
            }
        }
        __syncthreads();
    }
    // ---- epilogue ----
    float bvQ[4], bvV[4];
    #pragma unroll
    for (int nt = 0; nt < 4; ++nt) {
        bvQ[nt] = bQ[wv*64 + nt*16 + l15];
        bvV[nt] = bV[wv*64 + nt*16 + l15];
    }
    #pragma unroll
    for (int mt = 0; mt < 4; ++mt) {
        int rg = row0 + mt*16 + quad*4;
        #pragma unroll
        for (int r = 0; r < 4; ++r) {
            float* oq = oQ + (size_t)(rg + r)*osQ + wv*64 + l15;
            float* ov = oV + (size_t)(rg + r)*osV + wv*64 + l15;
            #pragma unroll
            for (int nt = 0; nt < 4; ++nt) {
                oq[nt*16] = acc[mt][nt][r]   + bvQ[nt];
                ov[nt*16] = acc[mt][nt+4][r] + bvV[nt];
            }
        }
    }
}

// ---------------- MFMA GEMM (single panel, 128-row): final projection -------
__global__ __launch_bounds__(256,2) void gemm_mfma(
    const float* __restrict__ A0, const float* __restrict__ A1,
    const ushort* __restrict__ Wh, const ushort* __restrict__ Wl,
    int w_base, const float* __restrict__ bias,
    float* __restrict__ o0, float* __restrict__ o1, int ostride)
{
    __shared__ ushort Ah[128*AST], Al[128*AST];   // 10240 B each
    int y = blockIdx.y;
    const float* A = y ? A1 : A0;
    float* out     = y ? o1 : o0;

    int tid = threadIdx.x;
    int row0 = blockIdx.x * 128;
    int wv = tid >> 6, lane = tid & 63;
    int quad = lane >> 4, l15 = lane & 15;

    f32x4 acc[8][4];
    #pragma unroll
    for (int mt = 0; mt < 8; ++mt)
        #pragma unroll
        for (int nt = 0; nt < 4; ++nt)
            acc[mt][nt] = f32x4{0.f, 0.f, 0.f, 0.f};

    int srow = tid >> 1;            // 0..127
    int skk  = (tid & 1) * 16;      // 0,16
    const float*  aptr = A  + (size_t)(row0 + srow)*256 + skk;
    const ushort* wfh = Wh + (size_t)(w_base + wv*64 + l15)*256 + quad*8;
    const ushort* wfl = Wl + (size_t)(w_base + wv*64 + l15)*256 + quad*8;

    for (int ck = 0; ck < 256; ck += 32) {
        short8 bh[4], bl[4];
        #pragma unroll
        for (int nt = 0; nt < 4; ++nt) {
            bh[nt] = *(const short8*)(wfh + (size_t)nt*16*256 + ck);
            bl[nt] = *(const short8*)(wfl + (size_t)nt*16*256 + ck);
        }
        float4 f0 = *(const float4*)(aptr + ck);
        float4 f1 = *(const float4*)(aptr + ck + 4);
        float4 f2 = *(const float4*)(aptr + ck + 8);
        float4 f3 = *(const float4*)(aptr + ck + 12);
        float fv[16] = {f0.x,f0.y,f0.z,f0.w, f1.x,f1.y,f1.z,f1.w,
                        f2.x,f2.y,f2.z,f2.w, f3.x,f3.y,f3.z,f3.w};
        ushort hu[16], lu[16];
        #pragma unroll
        for (int j = 0; j < 16; ++j) split1(fv[j], hu[j], lu[j]);
        *(uint4*)&Ah[srow*AST + skk]     = *(uint4*)&hu[0];
        *(uint4*)&Ah[srow*AST + skk + 8] = *(uint4*)&hu[8];
        *(uint4*)&Al[srow*AST + skk]     = *(uint4*)&lu[0];
        *(uint4*)&Al[srow*AST + skk + 8] = *(uint4*)&lu[8];
        __syncthreads();
        #pragma unroll
        for (int mt = 0; mt < 8; ++mt) {
            int r = mt*16 + l15;
            short8 ah = *(const short8*)&Ah[r*AST + quad*8];
            short8 al = *(const short8*)&Al[r*AST + quad*8];
            #pragma unroll
            for (int nt = 0; nt < 4; ++nt) {
                acc[mt][nt] = __builtin_amdgcn_mfma_f32_16x16x32_bf16(ah, bh[nt], acc[mt][nt], 0, 0, 0);
                acc[mt][nt] = __builtin_amdgcn_mfma_f32_16x16x32_bf16(ah, bl[nt], acc[mt][nt], 0, 0, 0);
                acc[mt][nt] = __builtin_amdgcn_mfma_f32_16x16x32_bf16(al, bh[nt], acc[mt][nt], 0, 0, 0);
            }
        }
        __syncthreads();
    }
    float bv[4];
    #pragma unroll
    for (int nt = 0; nt < 4; ++nt) bv[nt] = bias[wv*64 + nt*16 + l15];
    #pragma unroll
    for (int mt = 0; mt < 8; ++mt) {
        int rg = row0 + mt*16 + quad*4;
        #pragma unroll
        for (int r = 0; r < 4; ++r) {
            float* orow = out + (size_t)(rg + r)*ostride + wv*64 + l15;
            #pragma unroll
            for (int nt = 0; nt < 4; ++nt)
                orow[nt*16] = acc[mt][nt][r] + bv[nt];
        }
    }
}

// ---------------- routing: logits + diag=1.0 + top-4 (tie -> lower index) ----
__global__ __launch_bounds__(64) void route_kernel(
    const float* __restrict__ qwin, const float* __restrict__ kwin,
    int* __restrict__ idx)
{
    int tid = threadIdx.x;            // 64 = one wave
    int blk = blockIdx.x;             // [0, 2*N*64)
    int pair = blk >> 8;
    int rem = blk & 255;
    int n = rem >> 6, i = rem & 63;
    int qb = (pair == 0) ? 1 : 0;     // idx1 = route(q2w, k1w)
    int kb = (pair == 0) ? 0 : 1;
    const float* q = qwin + ((size_t)(qb*N_+n)*64 + i)*256;
    const float* k = kwin + ((size_t)(kb*N_+n)*64 + tid)*256;
    float s = 0.f;
    for (int c = 0; c < 256; ++c) s += q[c]*k[c];
    s *= SCALE_;
    if (tid == i) s = 1.0f;
    int* orow = idx + ((size_t)pair*N_*64 + rem)*4;
    for (int t = 0; t < 4; ++t) {
        float v = s; int bi = tid;
        #pragma unroll
        for (int off = 32; off > 0; off >>= 1) {
            float ov = __shfl_down(v, off);
            int   oi = __shfl_down(bi, off);
            if (ov > v || (ov == v && oi < bi)) { v = ov; bi = oi; }
        }
        bi = __shfl(bi, 0);
        if (tid == 0) orow[t] = bi;
        if (tid == bi) s = -3.0e38f;
    }
}

// ---------------- LePE: depthwise 3x3 'SAME' conv, both branches -------------
__global__ __launch_bounds__(256) void lepe_kernel(
    const float* __restrict__ v1, const float* __restrict__ v2,
    const float* __restrict__ lw, const float* __restrict__ lb,
    float* __restrict__ out1, float* __restrict__ out2)
{
    int c = threadIdx.x;
    int blk = blockIdx.x;           // 2*N*H*(W/32) = 4096
    int br  = blk >> 11;
    const float* v = br ? v2 : v1;
    float* out     = br ? out2 : out1;
    int wseg = blk & 3;
    int h = (blk >> 2) & 127;
    int n = (blk >> 9) & 3;
    float wk[9];
    #pragma unroll
    for (int t = 0; t < 9; ++t) wk[t] = lw[c*9 + t];
    float bias = lb[c];
    for (int px = 0; px < 32; ++px) {
        int w = wseg*32 + px;
        float acc = bias;
        #pragma unroll
        for (int ky = 0; ky < 3; ++ky) {
            int hh = h + ky - 1;
            if (hh < 0 || hh >= 128) continue;
            #pragma unroll
            for (int kx = 0; kx < 3; ++kx) {
                int wp = w + kx - 1;
                if (wp < 0 || wp >= 128) continue;
                acc += wk[ky*3+kx] * v[(((size_t)n*128 + hh)*128 + wp)*256 + c];
            }
        }
        out[(((size_t)n*128 + h)*128 + w)*256 + c] = acc;
    }
}

// ---------------- attention: MFMA + LDS alias, both branches merged ----------
#define KST 40   // K row stride (ushorts): 80B -> 2-way bank alias max
#define VST 72   // Vt / P row stride (ushorts): 144B -> 2-way
__global__ __launch_bounds__(256) void attn_kernel(
    const float* __restrict__ qA, const float* __restrict__ qB,
    const float* __restrict__ kvp, const int* __restrict__ idx,
    float* __restrict__ out1, float* __restrict__ out2)
{
    __shared__ __align__(16) char smem[19456];
    __shared__ int sel[4];
    ushort* Kh  = (ushort*)smem;
    ushort* Kl  = (ushort*)(smem + 5120);
    ushort* Vth = (ushort*)(smem + 10240);
    ushort* Vtl = (ushort*)(smem + 14848);

    int bx   = blockIdx.x;          // [0,512): br | n | win
    int br   = bx >> 8;
    int rem  = bx & 255;
    int n    = rem >> 6;
    int win  = rem & 63;
    int head = blockIdx.y;
    const float* qbuf = br ? qB : qA;
    float* out        = br ? out2 : out1;
    int tid  = threadIdx.x;
    int wv = tid >> 6, lane = tid & 63;
    int quad = lane >> 4, l15 = lane & 15;
    int wh = win >> 3, ww = win & 7;
    if (tid < 4) sel[tid] = idx[((size_t)br*N_*64 + (size_t)n*64 + win)*4 + tid];
    __syncthreads();
    const float* kvbase = kvp + (size_t)br*2097152 + (size_t)n*(64*16*512);

    // ---- stage K[64][32] hi/lo ----
    {
        int kkey = tid >> 2, kd = (tid & 3) * 8;
        const float* src = kvbase
            + (size_t)(sel[kkey>>4]*16 + (kkey&15))*512 + head*32 + kd;
        float4 f0 = *(const float4*)src;
        float4 f1 = *(const float4*)(src + 4);
        float fv[8] = {f0.x,f0.y,f0.z,f0.w, f1.x,f1.y,f1.z,f1.w};
        ushort hu[8], lu[8];
        #pragma unroll
        for (int j = 0; j < 8; ++j) split1(fv[j], hu[j], lu[j]);
        *(uint4*)&Kh[kkey*KST + kd] = *(uint4*)hu;
        *(uint4*)&Kl[kkey*KST + kd] = *(uint4*)lu;
    }
    // ---- stage Vt[32][64] hi/lo (transposed gather) ----
    {
        int vd = tid >> 3, vk = (tid & 7) * 8;
        int vcell = sel[vk >> 4]*16 + (vk & 15);
        float fv[8];
        #pragma unroll
        for (int j = 0; j < 8; ++j)
            fv[j] = kvbase[(size_t)(vcell + j)*512 + 256 + head*32 + vd];
        ushort hu[8], lu[8];
        #pragma unroll
        for (int j = 0; j < 8; ++j) split1(fv[j], hu[j], lu[j]);
        *(uint4*)&Vth[vd*VST + vk] = *(uint4*)hu;
        *(uint4*)&Vtl[vd*VST + vk] = *(uint4*)lu;
    }
    __syncthreads();
    // ---- hoist fragments: K (A-side), Vt (B-side) ----
    short8 kfh[4], kfl[4];
    #pragma unroll
    for (int kt = 0; kt < 4; ++kt) {
        kfh[kt] = *(const short8*)&Kh[(kt*16 + l15)*KST + quad*8];
        kfl[kt] = *(const short8*)&Kl[(kt*16 + l15)*KST + quad*8];
    }
    short8 vfh[2][2], vfl[2][2];   // [chunk c][d-tile nt]
    #pragma unroll
    for (int c = 0; c < 2; ++c)
        #pragma unroll
        for (int nt = 0; nt < 2; ++nt) {
            vfh[c][nt] = *(const short8*)&Vth[(nt*16 + l15)*VST + c*32 + quad*8];
            vfl[c][nt] = *(const short8*)&Vtl[(nt*16 + l15)*VST + c*32 + quad*8];
        }
    __syncthreads();   // staging LDS now dead -> safe to alias with P
    ushort* Ph = (ushort*)(smem + wv*4608);       // 16*VST us
    ushort* Pl = Ph + 1152;

    // ---- pixel tiles ----
    #pragma unroll
    for (int pt = 0; pt < 4; ++pt) {
        int ph = wv*4 + pt;
        const float* qp = qbuf
            + ((((size_t)n*128 + wh*16 + ph)*128 + ww*16 + l15)*256)
            + head*32 + quad*8;
        float4 q0 = *(const float4*)qp;
        float4 q1 = *(const float4*)(qp + 4);
        float qv[8] = {q0.x,q0.y,q0.z,q0.w, q1.x,q1.y,q1.z,q1.w};
        ushort qh_[8], ql_[8];
        #pragma unroll
        for (int j = 0; j < 8; ++j) split1(qv[j]*SCALE_, qh_[j], ql_[j]);
        short8 qh = *(short8*)qh_, ql = *(short8*)ql_;
        f32x4 s[4];
        #pragma unroll
        for (int kt = 0; kt < 4; ++kt) s[kt] = f32x4{0.f,0.f,0.f,0.f};
        #pragma unroll
        for (int kt = 0; kt < 4; ++kt) {
            s[kt] = __builtin_amdgcn_mfma_f32_16x16x32_bf16(kfh[kt], qh, s[kt], 0, 0, 0);
            s[kt] = __builtin_amdgcn_mfma_f32_16x16x32_bf16(kfh[kt], ql, s[kt], 0, 0, 0);
            s[kt] = __builtin_amdgcn_mfma_f32_16x16x32_bf16(kfl[kt], qh, s[kt], 0, 0, 0);
        }
        float m = -3.0e38f;
        #pragma unroll
        for (int kt = 0; kt < 4; ++kt)
            #pragma unroll
            for (int r = 0; r < 4; ++r) m = fmaxf(m, s[kt][r]);
        m = fmaxf(m, __shfl_xor(m, 16));
        m = fmaxf(m, __shfl_xor(m, 32));
        float p[16]; float lsum = 0.f;
        #pragma unroll
        for (int kt = 0; kt < 4; ++kt)
            #pragma unroll
            for (int r = 0; r < 4; ++r) {
                float pe = __expf(s[kt][r] - m);
                p[kt*4 + r] = pe;
                lsum += pe;
            }
        lsum += __shfl_xor(lsum, 16);
        lsum += __shfl_xor(lsum, 32);
        float inv = 1.f / lsum;
        #pragma unroll
        for (int kt = 0; kt < 4; ++kt) {
            ushort h4[4], l4[4];
            #pragma unroll
            for (int r = 0; r < 4; ++r) split1(p[kt*4 + r]*inv, h4[r], l4[r]);
            uint2 wph = { (uint)h4[0] | ((uint)h4[1] << 16),
                          (uint)h4[2] | ((uint)h4[3] << 16) };
            uint2 wpl = { (uint)l4[0] | ((uint)l4[1] << 16),
                          (uint)l4[2] | ((uint)l4[3] << 16) };
            *(uint2*)&Ph[l15*VST + kt*16 + quad*4] = wph;
            *(uint2*)&Pl[l15*VST + kt*16 + quad*4] = wpl;
        }
        short8 pfh[2], pfl[2];
        #pragma unroll
        for (int c = 0; c < 2; ++c) {
            pfh[c] = *(const short8*)&Ph[l15*VST + c*32 + quad*8];
            pfl[c] = *(const short8*)&Pl[l15*VST + c*32 + quad*8];
        }
        f32x4 o[2];
        o[0] = f32x4{0.f,0.f,0.f,0.f};
        o[1] = f32x4{0.f,0.f,0.f,0.f};
        #pragma unroll
        for (int c = 0; c < 2; ++c)
            #pragma unroll
            for (int nt = 0; nt < 2; ++nt) {
                o[nt] = __builtin_amdgcn_mfma_f32_16x16x32_bf16(pfh[c], vfh[c][nt], o[nt], 0, 0, 0);
                o[nt] = __builtin_amdgcn_mfma_f32_16x16x32_bf16(pfl[c], vfh[c][nt], o[nt], 0, 0, 0);
                o[nt] = __builtin_amdgcn_mfma_f32_16x16x32_bf16(pfh[c], vfl[c][nt], o[nt], 0, 0, 0);
            }
        #pragma unroll
        for (int r = 0; r < 4; ++r) {
            float* orow = out
                + ((((size_t)n*128 + wh*16 + ph)*128 + ww*16 + quad*4 + r)*256)
                + head*32 + l15;
            #pragma unroll
            for (int nt = 0; nt < 2; ++nt)
                orow[nt*16] += o[nt][r];
        }
    }
}

extern "C" void kernel_launch(void* const* d_in, const int* in_sizes, int n_in,
                              void* d_out, int out_size, void* d_ws, size_t ws_size,
                              hipStream_t stream)
{
    const float* x1   = (const float*)d_in[0];
    const float* x2   = (const float*)d_in[1];
    const float* Wqkv = (const float*)d_in[2];
    const float* bqkv = (const float*)d_in[3];
    const float* lw   = (const float*)d_in[4];
    const float* lb   = (const float*)d_in[5];
    const float* Wo   = (const float*)d_in[6];
    const float* bo   = (const float*)d_in[7];
    float* out1 = (float*)d_out;
    float* out2 = out1 + (size_t)TOK_*C_;

    float* ws    = (float*)d_ws;
    float* xpool = ws;                          //  2,097,152 f
    float* xwm   = xpool + 2097152;             //    131,072 f
    float* kvp   = xwm   + 131072;              //  4,194,304 f
    float* qwin  = kvp   + 4194304;             //    131,072 f
    float* kwin  = qwin  + 131072;              //    131,072 f
    int*   idx   = (int*)(kwin + 131072);       //      2,048 i
    ushort* Wh   = (ushort*)(idx + 2048);       //    262,144 us
    ushort* Wl   = Wh + 262144;                 //    262,144 us
    float* bufQ1 = (float*)(Wl + 262144);       // 16,777,216 f
    float* bufQ2 = bufQ1 + 16777216;            // 16,777,216 f
    float* bufV1 = bufQ2 + 16777216;            // 16,777,216 f
    float* bufV2 = bufV1 + 16777216;            // 16,777,216 f

    // 0) pre-split weights (Wqkv rows 0-767, Wo rows 768-1023)
    wsplit_kernel<<<dim3(256), dim3(256), 0, stream>>>(Wqkv, Wo, Wh, Wl);
    // 1) pooled image + window means (both branches)
    pool_kernel<<<dim3(512), dim3(256), 0, stream>>>(x1, x2, xpool, xwm);
    // 2) kv_pool: k + v panels from one xpool stage (M=8192)
    gemm_dual<<<dim3(128,1), dim3(256), 0, stream>>>(
        xpool, xpool, Wh, Wl, 256, 512, bqkv+256, bqkv+512,
        kvp, kvp+256, kvp, kvp+256, 512, 512);
    // 3) window-mean projections q + k from one xwm stage (M=512)
    gemm_dual<<<dim3(8,1), dim3(256), 0, stream>>>(
        xwm, xwm, Wh, Wl, 0, 256, bqkv, bqkv+256,
        qwin, kwin, qwin, kwin, 256, 256);
    // 4) routing (both pairs)
    route_kernel<<<dim3(512), dim3(64), 0, stream>>>(qwin, kwin, idx);
    // 5) q+v projections, both branches, one dispatch (M=65536 x2)
    gemm_dual<<<dim3(1024,2), dim3(256), 0, stream>>>(
        x1, x2, Wh, Wl, 0, 512, bqkv, bqkv+512,
        bufQ1, bufV1, bufQ2, bufV2, 256, 256);
    // 6) lepe (both branches) -> out1/out2
    lepe_kernel<<<dim3(4096), dim3(256), 0, stream>>>(bufV1, bufV2, lw, lb, out1, out2);
    // 7) attention (both branches): attend(q2,kv1,idx1)+=out1; attend(q1,kv2,idx2)+=out2
    attn_kernel<<<dim3(512,8), dim3(256), 0, stream>>>(bufQ2, bufQ1, kvp, idx, out1, out2);
    // 8) final projection, pair-batched, in-place (blocks own rows exclusively)
    gemm_mfma<<<dim3(512,2), dim3(256), 0, stream>>>(
        out1, out2, Wh, Wl, 768, bo, out1, out2, 256);
}

// Round 7
// 768.748 us; speedup vs baseline: 1.0049x; 1.0049x over previous
//
#include <hip/hip_runtime.h>

#define N_ 4
#define H_ 128
#define W_ 128
#define C_ 256
#define P2_ 64
#define CELLS_ 16
#define HEADS_ 8
#define TOPK_ 4
#define SCALE_ 0.0625f
#define TOK_ (N_*H_*W_)   // 65536

typedef short short8 __attribute__((ext_vector_type(8)));
typedef float f32x4  __attribute__((ext_vector_type(4)));

// fp32 -> bf16 hi (truncate, exact) + lo (RNE of residual)
__device__ __forceinline__ void split1(float f, ushort& h, ushort& l) {
    unsigned u = __float_as_uint(f);
    h = (ushort)(u >> 16);
    float hif = __uint_as_float(u & 0xFFFF0000u);
    unsigned ul = __float_as_uint(f - hif);
    ul = ul + 0x7FFFu + ((ul >> 16) & 1u);
    l = (ushort)(ul >> 16);
}

// ---------------- pooling: xpool (4x4 cells) + window means ----------------
__global__ __launch_bounds__(256) void pool_kernel(
    const float* __restrict__ x1, const float* __restrict__ x2,
    float* __restrict__ xpool, float* __restrict__ xwm)
{
    int c = threadIdx.x;
    int blk = blockIdx.x;            // [0, 2*N*P2)
    int b   = blk >> 8;
    int rem = blk & 255;
    int n   = rem >> 6;
    int win = rem & 63;
    int wh = win >> 3, ww = win & 7;
    const float* x = (b ? x2 : x1);
    size_t nbase = (size_t)n * H_ * W_ * C_;
    size_t prow = (size_t)(b*N_ + n)*P2_ + win;
    float wsum = 0.f;
    #pragma unroll
    for (int cell = 0; cell < 16; ++cell) {
        int a = cell >> 2, d = cell & 3;
        int h0 = wh*16 + a*4, w0 = ww*16 + d*4;
        float s = 0.f;
        #pragma unroll
        for (int dy = 0; dy < 4; ++dy)
            #pragma unroll
            for (int dx = 0; dx < 4; ++dx)
                s += x[nbase + ((size_t)(h0+dy)*W_ + (w0+dx))*C_ + c];
        xpool[(prow*CELLS_ + cell)*C_ + c] = s * (1.f/16.f);
        wsum += s;
    }
    xwm[prow*C_ + c] = wsum * (1.f/256.f);
}

// ---------------- W pre-split into MFMA B-frag layout -----------------------
// Wf[((g*8 + c)*64 + lane)*8 + j] = W[g*16 + (lane&15)][c*32 + (lane>>4)*8 + j]
// (combined rows: [0,768)=Wqkv, [768,1024)=Wo). Tile g stride = 4096 ushorts,
// chunk c stride = 512. B-frag loads become base + lane*16B -> contiguous 1KB.
__global__ __launch_bounds__(256) void wsplit_kernel(
    const float* __restrict__ Wqkv, const float* __restrict__ Wo,
    ushort* __restrict__ Wfh, ushort* __restrict__ Wfl)
{
    int t = blockIdx.x*256 + threadIdx.x;   // [0, 32768)
    int lane = t & 63, c = (t >> 6) & 7, g = t >> 9;
    int row = g*16 + (lane & 15);
    int k   = c*32 + (lane >> 4)*8;
    const float* src = (row < 768) ? (Wqkv + (size_t)row*256 + k)
                                   : (Wo + (size_t)(row - 768)*256 + k);
    float4 f0 = *(const float4*)src;
    float4 f1 = *(const float4*)(src + 4);
    float fv[8] = {f0.x,f0.y,f0.z,f0.w, f1.x,f1.y,f1.z,f1.w};
    ushort hu[8], lu[8];
    #pragma unroll
    for (int j = 0; j < 8; ++j) split1(fv[j], hu[j], lu[j]);
    size_t dst = ((size_t)(g*8 + c)*64 + lane)*8;
    *(uint4*)&Wfh[dst] = *(uint4*)hu;
    *(uint4*)&Wfl[dst] = *(uint4*)lu;
}

#define AST2 132   // half-K LDS row stride (ushorts) = 264 B -> <=2-way alias

// ---------------- frag GEMM, dual panel: 64 rows x 512 cols -----------------
// 4 waves; waves 0,1 -> Q panel, 2,3 -> V panel; wave-tile 64x128.
// A staged by FULL-ROW coalesced reads (half-K at a time), split once;
// B-frags contiguous 1KB wave-loads from pre-swizzled Wf. K-loop is
// barrier-free (3 barriers/block total). blockIdx.y batches slices.
__global__ __launch_bounds__(256,2) void gemm_frag2(
    const float* __restrict__ A0, const float* __restrict__ A1,
    const ushort* __restrict__ Wfh, const ushort* __restrict__ Wfl,
    int wbQ, int wbV,
    const float* __restrict__ bQ, const float* __restrict__ bV,
    float* __restrict__ oQ0, float* __restrict__ oV0,
    float* __restrict__ oQ1, float* __restrict__ oV1,
    int osQ, int osV)
{
    __shared__ ushort Ah[64*AST2], Al[64*AST2];   // 16896 B each
    int y = blockIdx.y;
    const float* A = y ? A1 : A0;
    float* oQ = y ? oQ1 : oQ0;
    float* oV = y ? oV1 : oV0;
    int tid = threadIdx.x, row0 = blockIdx.x*64;
    int wv = tid >> 6, lane = tid & 63;
    int quad = lane >> 4, l15 = lane & 15;
    int isV = wv >> 1, colb = (wv & 1)*128;
    int wb = isV ? wbV : wbQ;
    // tile stride = 4096 ushorts (8 chunks x 512)
    const ushort* bfh = Wfh + ((size_t)((wb >> 4) + (wv & 1)*8)*4096 + lane*8);
    const ushort* bfl = Wfl + ((size_t)((wb >> 4) + (wv & 1)*8)*4096 + lane*8);

    f32x4 acc[4][8];
    #pragma unroll
    for (int mt = 0; mt < 4; ++mt)
        #pragma unroll
        for (int nt = 0; nt < 8; ++nt)
            acc[mt][nt] = f32x4{0.f,0.f,0.f,0.f};

    #pragma unroll
    for (int half = 0; half < 2; ++half) {
        if (half) __syncthreads();          // all reads of prev half done
        // ---- stage 64 x 128 half-K: full-row coalesced loads ----
        #pragma unroll
        for (int rr = 0; rr < 8; ++rr) {
            int row = wv*16 + rr*2 + (lane >> 5);
            int col = (lane & 31)*4;
            float4 f = *(const float4*)(A + (size_t)(row0+row)*256 + half*128 + col);
            float fv[4] = {f.x, f.y, f.z, f.w};
            ushort hu[4], lu[4];
            #pragma unroll
            for (int j = 0; j < 4; ++j) split1(fv[j], hu[j], lu[j]);
            *(uint2*)&Ah[row*AST2 + col] = *(uint2*)hu;
            *(uint2*)&Al[row*AST2 + col] = *(uint2*)lu;
        }
        __syncthreads();
        // ---- barrier-free compute: 4 k-chunks of this half ----
        #pragma unroll
        for (int cc = 0; cc < 4; ++cc) {
            int c = half*4 + cc;
            short8 ah[4], al[4];
            #pragma unroll
            for (int mt = 0; mt < 4; ++mt) {
                ah[mt] = *(const short8*)&Ah[(mt*16 + l15)*AST2 + cc*32 + quad*8];
                al[mt] = *(const short8*)&Al[(mt*16 + l15)*AST2 + cc*32 + quad*8];
            }
            #pragma unroll
            for (int hf = 0; hf < 2; ++hf) {
                short8 bh[4], bl[4];
                #pragma unroll
                for (int q = 0; q < 4; ++q) {
                    int nt = hf*4 + q;
                    bh[q] = *(const short8*)(bfh + (size_t)nt*4096 + c*512);
                    bl[q] = *(const short8*)(bfl + (size_t)nt*4096 + c*512);
                }
                #pragma unroll
                for (int mt = 0; mt < 4; ++mt)
                    #pragma unroll
                    for (int q = 0; q < 4; ++q) {
                        int nt = hf*4 + q;
                        acc[mt][nt] = __builtin_amdgcn_mfma_f32_16x16x32_bf16(ah[mt], bh[q], acc[mt][nt], 0, 0, 0);
                        acc[mt][nt] = __builtin_amdgcn_mfma_f32_16x16x32_bf16(ah[mt], bl[q], acc[mt][nt], 0, 0, 0);
                        acc[mt][nt] = __builtin_amdgcn_mfma_f32_16x16x32_bf16(al[mt], bh[q], acc[mt][nt], 0, 0, 0);
                    }
            }
        }
    }
    // ---- epilogue ----
    float* op = isV ? oV : oQ;
    int os = isV ? osV : osQ;
    const float* bp = isV ? bV : bQ;
    float bv[8];
    #pragma unroll
    for (int nt = 0; nt < 8; ++nt) bv[nt] = bp[colb + nt*16 + l15];
    #pragma unroll
    for (int mt = 0; mt < 4; ++mt) {
        int rg = row0 + mt*16 + quad*4;
        #pragma unroll
        for (int r = 0; r < 4; ++r) {
            float* orow = op + (size_t)(rg + r)*os + colb + l15;
            #pragma unroll
            for (int nt = 0; nt < 8; ++nt)
                orow[nt*16] = acc[mt][nt][r] + bv[nt];
        }
    }
}

// ---------------- frag GEMM, single panel: 64 rows x 256 cols ---------------
// Same structure; wave-tile 64x64. Used for the final projection over the
// contiguous out1||out2 rows (in-place safe: block reads only its own rows,
// fully staged before epilogue writes).
__global__ __launch_bounds__(256,2) void gemm_frag1(
    const float* __restrict__ A,
    const ushort* __restrict__ Wfh, const ushort* __restrict__ Wfl,
    int wb, const float* __restrict__ bias,
    float* __restrict__ out, int os)
{
    __shared__ ushort Ah[64*AST2], Al[64*AST2];
    int tid = threadIdx.x, row0 = blockIdx.x*64;
    int wv = tid >> 6, lane = tid & 63;
    int quad = lane >> 4, l15 = lane & 15;
    int colb = wv*64;
    // tile stride = 4096 ushorts
    const ushort* bfh = Wfh + ((size_t)((wb >> 4) + wv*4)*4096 + lane*8);
    const ushort* bfl = Wfl + ((size_t)((wb >> 4) + wv*4)*4096 + lane*8);

    f32x4 acc[4][4];
    #pragma unroll
    for (int mt = 0; mt < 4; ++mt)
        #pragma unroll
        for (int nt = 0; nt < 4; ++nt)
            acc[mt][nt] = f32x4{0.f,0.f,0.f,0.f};

    #pragma unroll
    for (int half = 0; half < 2; ++half) {
        if (half) __syncthreads();
        #pragma unroll
        for (int rr = 0; rr < 8; ++rr) {
            int row = wv*16 + rr*2 + (lane >> 5);
            int col = (lane & 31)*4;
            float4 f = *(const float4*)(A + (size_t)(row0+row)*256 + half*128 + col);
            float fv[4] = {f.x, f.y, f.z, f.w};
            ushort hu[4], lu[4];
            #pragma unroll
            for (int j = 0; j < 4; ++j) split1(fv[j], hu[j], lu[j]);
            *(uint2*)&Ah[row*AST2 + col] = *(uint2*)hu;
            *(uint2*)&Al[row*AST2 + col] = *(uint2*)lu;
        }
        __syncthreads();
        #pragma unroll
        for (int cc = 0; cc < 4; ++cc) {
            int c = half*4 + cc;
            short8 bh[4], bl[4];
            #pragma unroll
            for (int nt = 0; nt < 4; ++nt) {
                bh[nt] = *(const short8*)(bfh + (size_t)nt*4096 + c*512);
                bl[nt] = *(const short8*)(bfl + (size_t)nt*4096 + c*512);
            }
            #pragma unroll
            for (int mt = 0; mt < 4; ++mt) {
                short8 ah = *(const short8*)&Ah[(mt*16 + l15)*AST2 + cc*32 + quad*8];
                short8 al = *(const short8*)&Al[(mt*16 + l15)*AST2 + cc*32 + quad*8];
                #pragma unroll
                for (int nt = 0; nt < 4; ++nt) {
                    acc[mt][nt] = __builtin_amdgcn_mfma_f32_16x16x32_bf16(ah, bh[nt], acc[mt][nt], 0, 0, 0);
                    acc[mt][nt] = __builtin_amdgcn_mfma_f32_16x16x32_bf16(ah, bl[nt], acc[mt][nt], 0, 0, 0);
                    acc[mt][nt] = __builtin_amdgcn_mfma_f32_16x16x32_bf16(al, bh[nt], acc[mt][nt], 0, 0, 0);
                }
            }
        }
    }
    float bv[4];
    #pragma unroll
    for (int nt = 0; nt < 4; ++nt) bv[nt] = bias[colb + nt*16 + l15];
    #pragma unroll
    for (int mt = 0; mt < 4; ++mt) {
        int rg = row0 + mt*16 + quad*4;
        #pragma unroll
        for (int r = 0; r < 4; ++r) {
            float* orow = out + (size_t)(rg + r)*os + colb + l15;
            #pragma unroll
            for (int nt = 0; nt < 4; ++nt)
                orow[nt*16] = acc[mt][nt][r] + bv[nt];
        }
    }
}

// ---------------- routing: logits + diag=1.0 + top-4 (tie -> lower index) ----
__global__ __launch_bounds__(64) void route_kernel(
    const float* __restrict__ qwin, const float* __restrict__ kwin,
    int* __restrict__ idx)
{
    int tid = threadIdx.x;            // 64 = one wave
    int blk = blockIdx.x;             // [0, 2*N*64)
    int pair = blk >> 8;
    int rem = blk & 255;
    int n = rem >> 6, i = rem & 63;
    int qb = (pair == 0) ? 1 : 0;     // idx1 = route(q2w, k1w)
    int kb = (pair == 0) ? 0 : 1;
    const float* q = qwin + ((size_t)(qb*N_+n)*64 + i)*256;
    const float* k = kwin + ((size_t)(kb*N_+n)*64 + tid)*256;
    float s = 0.f;
    for (int c = 0; c < 256; ++c) s += q[c]*k[c];
    s *= SCALE_;
    if (tid == i) s = 1.0f;
    int* orow = idx + ((size_t)pair*N_*64 + rem)*4;
    for (int t = 0; t < 4; ++t) {
        float v = s; int bi = tid;
        #pragma unroll
        for (int off = 32; off > 0; off >>= 1) {
            float ov = __shfl_down(v, off);
            int   oi = __shfl_down(bi, off);
            if (ov > v || (ov == v && oi < bi)) { v = ov; bi = oi; }
        }
        bi = __shfl(bi, 0);
        if (tid == 0) orow[t] = bi;
        if (tid == bi) s = -3.0e38f;
    }
}

// ---------------- LePE: 3x3 depthwise conv, sliding-window (3 loads/px) -----
__global__ __launch_bounds__(256) void lepe_kernel(
    const float* __restrict__ v1, const float* __restrict__ v2,
    const float* __restrict__ lw, const float* __restrict__ lb,
    float* __restrict__ out1, float* __restrict__ out2)
{
    int c = threadIdx.x;
    int blk = blockIdx.x;           // 2*N*H = 1024
    int br = blk >> 9;
    int rem = blk & 511;
    int n = rem >> 7, h = rem & 127;
    const float* v = br ? v2 : v1;
    float* out     = br ? out2 : out1;
    float wk[9];
    #pragma unroll
    for (int t = 0; t < 9; ++t) wk[t] = lw[c*9 + t];
    float bias = lb[c];
    const float* rm = v + (((size_t)n*128 + h)*128)*256 + c;
    const float* r0 = rm - 128*256;
    const float* rb = rm + 128*256;
    bool vt = (h > 0), vb = (h < 127);
    float* op = out + (((size_t)n*128 + h)*128)*256 + c;
    float t0=0.f, m0=0.f, b0=0.f;
    float t1 = vt ? r0[0] : 0.f;
    float m1 = rm[0];
    float b1 = vb ? rb[0] : 0.f;
    float t2 = vt ? r0[256] : 0.f;
    float m2 = rm[256];
    float b2 = vb ? rb[256] : 0.f;
    for (int w = 0; w < 128; ++w) {
        float acc = bias
            + wk[0]*t0 + wk[1]*t1 + wk[2]*t2
            + wk[3]*m0 + wk[4]*m1 + wk[5]*m2
            + wk[6]*b0 + wk[7]*b1 + wk[8]*b2;
        op[(size_t)w*256] = acc;
        t0 = t1; m0 = m1; b0 = b1;
        t1 = t2; m1 = m2; b1 = b2;
        if (w + 2 < 128) {
            size_t o = (size_t)(w + 2)*256;
            t2 = vt ? r0[o] : 0.f;
            m2 = rm[o];
            b2 = vb ? rb[o] : 0.f;
        } else { t2 = 0.f; m2 = 0.f; b2 = 0.f; }
    }
}

// ---------------- attention: MFMA + LDS alias, both branches merged ----------
#define KST 40   // K row stride (ushorts): 80B -> 2-way bank alias max
#define VST 72   // Vt / P row stride (ushorts): 144B -> 2-way
__global__ __launch_bounds__(256) void attn_kernel(
    const float* __restrict__ qA, const float* __restrict__ qB,
    const float* __restrict__ kvp, const int* __restrict__ idx,
    float* __restrict__ out1, float* __restrict__ out2)
{
    __shared__ __align__(16) char smem[19456];
    __shared__ int sel[4];
    ushort* Kh  = (ushort*)smem;
    ushort* Kl  = (ushort*)(smem + 5120);
    ushort* Vth = (ushort*)(smem + 10240);
    ushort* Vtl = (ushort*)(smem + 14848);

    int bx   = blockIdx.x;          // [0,512): br | n | win
    int br   = bx >> 8;
    int rem  = bx & 255;
    int n    = rem >> 6;
    int win  = rem & 63;
    int head = blockIdx.y;
    const float* qbuf = br ? qB : qA;
    float* out        = br ? out2 : out1;
    int tid  = threadIdx.x;
    int wv = tid >> 6, lane = tid & 63;
    int quad = lane >> 4, l15 = lane & 15;
    int wh = win >> 3, ww = win & 7;
    if (tid < 4) sel[tid] = idx[((size_t)br*N_*64 + (size_t)n*64 + win)*4 + tid];
    __syncthreads();
    const float* kvbase = kvp + (size_t)br*2097152 + (size_t)n*(64*16*512);

    // ---- stage K[64][32] hi/lo ----
    {
        int kkey = tid >> 2, kd = (tid & 3) * 8;
        const float* src = kvbase
            + (size_t)(sel[kkey>>4]*16 + (kkey&15))*512 + head*32 + kd;
        float4 f0 = *(const float4*)src;
        float4 f1 = *(const float4*)(src + 4);
        float fv[8] = {f0.x,f0.y,f0.z,f0.w, f1.x,f1.y,f1.z,f1.w};
        ushort hu[8], lu[8];
        #pragma unroll
        for (int j = 0; j < 8; ++j) split1(fv[j], hu[j], lu[j]);
        *(uint4*)&Kh[kkey*KST + kd] = *(uint4*)hu;
        *(uint4*)&Kl[kkey*KST + kd] = *(uint4*)lu;
    }
    // ---- stage Vt[32][64] hi/lo (transposed gather) ----
    {
        int vd = tid >> 3, vk = (tid & 7) * 8;
        int vcell = sel[vk >> 4]*16 + (vk & 15);
        float fv[8];
        #pragma unroll
        for (int j = 0; j < 8; ++j)
            fv[j] = kvbase[(size_t)(vcell + j)*512 + 256 + head*32 + vd];
        ushort hu[8], lu[8];
        #pragma unroll
        for (int j = 0; j < 8; ++j) split1(fv[j], hu[j], lu[j]);
        *(uint4*)&Vth[vd*VST + vk] = *(uint4*)hu;
        *(uint4*)&Vtl[vd*VST + vk] = *(uint4*)lu;
    }
    __syncthreads();
    // ---- hoist fragments: K (A-side), Vt (B-side) ----
    short8 kfh[4], kfl[4];
    #pragma unroll
    for (int kt = 0; kt < 4; ++kt) {
        kfh[kt] = *(const short8*)&Kh[(kt*16 + l15)*KST + quad*8];
        kfl[kt] = *(const short8*)&Kl[(kt*16 + l15)*KST + quad*8];
    }
    short8 vfh[2][2], vfl[2][2];   // [chunk c][d-tile nt]
    #pragma unroll
    for (int c = 0; c < 2; ++c)
        #pragma unroll
        for (int nt = 0; nt < 2; ++nt) {
            vfh[c][nt] = *(const short8*)&Vth[(nt*16 + l15)*VST + c*32 + quad*8];
            vfl[c][nt] = *(const short8*)&Vtl[(nt*16 + l15)*VST + c*32 + quad*8];
        }
    __syncthreads();   // staging LDS now dead -> safe to alias with P
    ushort* Ph = (ushort*)(smem + wv*4608);       // 16*VST us
    ushort* Pl = Ph + 1152;

    // ---- pixel tiles ----
    #pragma unroll
    for (int pt = 0; pt < 4; ++pt) {
        int ph = wv*4 + pt;
        const float* qp = qbuf
            + ((((size_t)n*128 + wh*16 + ph)*128 + ww*16 + l15)*256)
            + head*32 + quad*8;
        float4 q0 = *(const float4*)qp;
        float4 q1 = *(const float4*)(qp + 4);
        float qv[8] = {q0.x,q0.y,q0.z,q0.w, q1.x,q1.y,q1.z,q1.w};
        ushort qh_[8], ql_[8];
        #pragma unroll
        for (int j = 0; j < 8; ++j) split1(qv[j]*SCALE_, qh_[j], ql_[j]);
        short8 qh = *(short8*)qh_, ql = *(short8*)ql_;
        f32x4 s[4];
        #pragma unroll
        for (int kt = 0; kt < 4; ++kt) s[kt] = f32x4{0.f,0.f,0.f,0.f};
        #pragma unroll
        for (int kt = 0; kt < 4; ++kt) {
            s[kt] = __builtin_amdgcn_mfma_f32_16x16x32_bf16(kfh[kt], qh, s[kt], 0, 0, 0);
            s[kt] = __builtin_amdgcn_mfma_f32_16x16x32_bf16(kfh[kt], ql, s[kt], 0, 0, 0);
            s[kt] = __builtin_amdgcn_mfma_f32_16x16x32_bf16(kfl[kt], qh, s[kt], 0, 0, 0);
        }
        float m = -3.0e38f;
        #pragma unroll
        for (int kt = 0; kt < 4; ++kt)
            #pragma unroll
            for (int r = 0; r < 4; ++r) m = fmaxf(m, s[kt][r]);
        m = fmaxf(m, __shfl_xor(m, 16));
        m = fmaxf(m, __shfl_xor(m, 32));
        float p[16]; float lsum = 0.f;
        #pragma unroll
        for (int kt = 0; kt < 4; ++kt)
            #pragma unroll
            for (int r = 0; r < 4; ++r) {
                float pe = __expf(s[kt][r] - m);
                p[kt*4 + r] = pe;
                lsum += pe;
            }
        lsum += __shfl_xor(lsum, 16);
        lsum += __shfl_xor(lsum, 32);
        float inv = 1.f / lsum;
        #pragma unroll
        for (int kt = 0; kt < 4; ++kt) {
            ushort h4[4], l4[4];
            #pragma unroll
            for (int r = 0; r < 4; ++r) split1(p[kt*4 + r]*inv, h4[r], l4[r]);
            uint2 wph = { (uint)h4[0] | ((uint)h4[1] << 16),
                          (uint)h4[2] | ((uint)h4[3] << 16) };
            uint2 wpl = { (uint)l4[0] | ((uint)l4[1] << 16),
                          (uint)l4[2] | ((uint)l4[3] << 16) };
            *(uint2*)&Ph[l15*VST + kt*16 + quad*4] = wph;
            *(uint2*)&Pl[l15*VST + kt*16 + quad*4] = wpl;
        }
        short8 pfh[2], pfl[2];
        #pragma unroll
        for (int c = 0; c < 2; ++c) {
            pfh[c] = *(const short8*)&Ph[l15*VST + c*32 + quad*8];
            pfl[c] = *(const short8*)&Pl[l15*VST + c*32 + quad*8];
        }
        f32x4 o[2];
        o[0] = f32x4{0.f,0.f,0.f,0.f};
        o[1] = f32x4{0.f,0.f,0.f,0.f};
        #pragma unroll
        for (int c = 0; c < 2; ++c)
            #pragma unroll
            for (int nt = 0; nt < 2; ++nt) {
                o[nt] = __builtin_amdgcn_mfma_f32_16x16x32_bf16(pfh[c], vfh[c][nt], o[nt], 0, 0, 0);
                o[nt] = __builtin_amdgcn_mfma_f32_16x16x32_bf16(pfl[c], vfh[c][nt], o[nt], 0, 0, 0);
                o[nt] = __builtin_amdgcn_mfma_f32_16x16x32_bf16(pfh[c], vfl[c][nt], o[nt], 0, 0, 0);
            }
        #pragma unroll
        for (int r = 0; r < 4; ++r) {
            float* orow = out
                + ((((size_t)n*128 + wh*16 + ph)*128 + ww*16 + quad*4 + r)*256)
                + head*32 + l15;
            #pragma unroll
            for (int nt = 0; nt < 2; ++nt)
                orow[nt*16] += o[nt][r];
        }
    }
}

extern "C" void kernel_launch(void* const* d_in, const int* in_sizes, int n_in,
                              void* d_out, int out_size, void* d_ws, size_t ws_size,
                              hipStream_t stream)
{
    const float* x1   = (const float*)d_in[0];
    const float* x2   = (const float*)d_in[1];
    const float* Wqkv = (const float*)d_in[2];
    const float* bqkv = (const float*)d_in[3];
    const float* lw   = (const float*)d_in[4];
    const float* lb   = (const float*)d_in[5];
    const float* Wo   = (const float*)d_in[6];
    const float* bo   = (const float*)d_in[7];
    float* out1 = (float*)d_out;
    float* out2 = out1 + (size_t)TOK_*C_;

    float* ws    = (float*)d_ws;
    float* xpool = ws;                          //  2,097,152 f
    float* xwm   = xpool + 2097152;             //    131,072 f
    float* kvp   = xwm   + 131072;              //  4,194,304 f
    float* qwin  = kvp   + 4194304;             //    131,072 f
    float* kwin  = qwin  + 131072;              //    131,072 f
    int*   idx   = (int*)(kwin + 131072);       //      2,048 i
    ushort* Wfh  = (ushort*)(idx + 2048);       //    262,144 us
    ushort* Wfl  = Wfh + 262144;                //    262,144 us
    float* bufQ1 = (float*)(Wfl + 262144);      // 16,777,216 f
    float* bufQ2 = bufQ1 + 16777216;            // 16,777,216 f
    float* bufV1 = bufQ2 + 16777216;            // 16,777,216 f
    float* bufV2 = bufV1 + 16777216;            // 16,777,216 f

    // 0) pre-split weights into frag layout
    wsplit_kernel<<<dim3(128), dim3(256), 0, stream>>>(Wqkv, Wo, Wfh, Wfl);
    // 1) pooled image + window means (both branches)
    pool_kernel<<<dim3(512), dim3(256), 0, stream>>>(x1, x2, xpool, xwm);
    // 2) kv_pool: k + v panels (M=8192)
    gemm_frag2<<<dim3(128,1), dim3(256), 0, stream>>>(
        xpool, xpool, Wfh, Wfl, 256, 512, bqkv+256, bqkv+512,
        kvp, kvp+256, kvp, kvp+256, 512, 512);
    // 3) window-mean projections q + k (M=512)
    gemm_frag2<<<dim3(8,1), dim3(256), 0, stream>>>(
        xwm, xwm, Wfh, Wfl, 0, 256, bqkv, bqkv+256,
        qwin, kwin, qwin, kwin, 256, 256);
    // 4) routing (both pairs)
    route_kernel<<<dim3(512), dim3(64), 0, stream>>>(qwin, kwin, idx);
    // 5) q+v projections, both branches, one dispatch (M=65536 x2)
    gemm_frag2<<<dim3(1024,2), dim3(256), 0, stream>>>(
        x1, x2, Wfh, Wfl, 0, 512, bqkv, bqkv+512,
        bufQ1, bufV1, bufQ2, bufV2, 256, 256);
    // 6) lepe (both branches) -> out1/out2
    lepe_kernel<<<dim3(1024), dim3(256), 0, stream>>>(bufV1, bufV2, lw, lb, out1, out2);
    // 7) attention (both branches): attend(q2,kv1,idx1)+=out1; attend(q1,kv2,idx2)+=out2
    attn_kernel<<<dim3(512,8), dim3(256), 0, stream>>>(bufQ2, bufQ1, kvp, idx, out1, out2);
    // 8) final projection over contiguous out1||out2 rows (M=131072), in-place
    gemm_frag1<<<dim3(2048,1), dim3(256), 0, stream>>>(
        out1, Wfh, Wfl, 768, bo, out1, 256);
}